// Round 1
// baseline (2538.631 us; speedup 1.0000x reference)
//
#include <hip/hip_runtime.h>
#include <hip/hip_bf16.h>
#include <math.h>

#define NATOMS 3072
#define NBONDS 12288
#define NGRAPH 64
#define DIM 256
#define NH 8
#define HDIM 32
#define NLAYER 4
#define AFD 74
#define BFD 12
#define LNEPS 1e-5f

// ---------------- input projections ----------------
__global__ __launch_bounds__(256) void atom_proj_kernel(
    const float* __restrict__ feat, const float* __restrict__ w,
    const float* __restrict__ b, float* __restrict__ out) {
  __shared__ float x[AFD];
  const int a = blockIdx.x, t = threadIdx.x;
  if (t < AFD) x[t] = feat[a * AFD + t];
  __syncthreads();
  float acc = b[t];
  const float* wr = w + t * AFD;
  for (int k = 0; k < AFD; ++k) acc = fmaf(wr[k], x[k], acc);
  out[a * DIM + t] = acc;
}

__global__ __launch_bounds__(256) void bond_proj_kernel(
    const float* __restrict__ feat, const float* __restrict__ w,
    const float* __restrict__ b, float* __restrict__ out) {
  __shared__ float x[BFD];
  const int e = blockIdx.x, t = threadIdx.x;
  if (t < BFD) x[t] = feat[e * BFD + t];
  __syncthreads();
  float acc = b[t];
  const float* wr = w + t * BFD;
  #pragma unroll
  for (int k = 0; k < BFD; ++k) acc = fmaf(wr[k], x[k], acc);
  out[e * DIM + t] = acc;
}

// ---------------- bond conv: gather -> [12288,512]x[512,256]^T -> relu -> scatter-add ----------------
// 8 bonds per block; messages staged in LDS; thread t owns output dim t for all 8 bonds.
__global__ __launch_bounds__(256) void conv_kernel(
    const float* __restrict__ atom_h, const float* __restrict__ bond_h,
    const int* __restrict__ src, const int* __restrict__ tgt,
    const float* __restrict__ w, const float* __restrict__ b,
    float* __restrict__ agg) {
  __shared__ float M[8][512];  // 16 KB
  const int e0 = blockIdx.x * 8, t = threadIdx.x;
  for (int idx = t; idx < 8 * 512; idx += 256) {
    const int be = idx >> 9, c = idx & 511;
    const int e = e0 + be;
    float v;
    if (c < 256) v = atom_h[src[e] * DIM + c] + bond_h[e * DIM + c];
    else         v = atom_h[tgt[e] * DIM + (c - 256)];
    M[be][c] = v;
  }
  __syncthreads();
  float acc[8];
  const float bb = b[t];
  #pragma unroll
  for (int i = 0; i < 8; ++i) acc[i] = bb;
  const float4* wr = (const float4*)(w + (size_t)t * 512);
  for (int k4 = 0; k4 < 128; ++k4) {
    const float4 w4 = wr[k4];
    #pragma unroll
    for (int be = 0; be < 8; ++be) {
      const float4 m4 = *(const float4*)&M[be][k4 << 2];  // uniform addr -> broadcast
      acc[be] += w4.x * m4.x + w4.y * m4.y + w4.z * m4.z + w4.w * m4.w;
    }
  }
  #pragma unroll
  for (int be = 0; be < 8; ++be) {
    const float v = fmaxf(acc[be], 0.f);
    atomicAdd(&agg[(size_t)tgt[e0 + be] * DIM + t], v);
  }
}

// ---------------- qkv projection: [3072,256] x [768,256]^T + bias ----------------
// 8 atoms per block; thread t owns output dims {t, t+256, t+512}.
__global__ __launch_bounds__(256) void qkv_kernel(
    const float* __restrict__ x, const float* __restrict__ w,
    const float* __restrict__ b, float* __restrict__ qkv) {
  __shared__ float X[8][256];  // 8 KB
  const int a0 = blockIdx.x * 8, t = threadIdx.x;
  for (int idx = t; idx < 8 * 256; idx += 256) {
    const int a = idx >> 8, c = idx & 255;
    X[a][c] = x[(size_t)(a0 + a) * DIM + c];
  }
  __syncthreads();
  float aq[8], ak[8], av[8];
  const float bq = b[t], bk = b[t + 256], bv = b[t + 512];
  #pragma unroll
  for (int a = 0; a < 8; ++a) { aq[a] = bq; ak[a] = bk; av[a] = bv; }
  const float4* wq = (const float4*)(w + (size_t)t * 256);
  const float4* wk = (const float4*)(w + (size_t)(t + 256) * 256);
  const float4* wv = (const float4*)(w + (size_t)(t + 512) * 256);
  for (int k4 = 0; k4 < 64; ++k4) {
    const float4 q4 = wq[k4], k4v = wk[k4], v4 = wv[k4];
    #pragma unroll
    for (int a = 0; a < 8; ++a) {
      const float4 x4 = *(const float4*)&X[a][k4 << 2];
      aq[a] += q4.x * x4.x + q4.y * x4.y + q4.z * x4.z + q4.w * x4.w;
      ak[a] += k4v.x * x4.x + k4v.y * x4.y + k4v.z * x4.z + k4v.w * x4.w;
      av[a] += v4.x * x4.x + v4.y * x4.y + v4.z * x4.z + v4.w * x4.w;
    }
  }
  #pragma unroll
  for (int a = 0; a < 8; ++a) {
    const size_t row = (size_t)(a0 + a) * (3 * DIM);
    qkv[row + t] = aq[a];
    qkv[row + 256 + t] = ak[a];
    qkv[row + 512 + t] = av[a];
  }
}

// ---------------- flash attention, one head x 32-query tile per block ----------------
// thread t: q-row = t>>3, handles 4 keys (scores) / 4 dims (PV), sub = t&7.
template <bool MASKED>
__global__ __launch_bounds__(256) void attn_kernel(
    const float* __restrict__ qkv, const int* __restrict__ bidx,
    float* __restrict__ out) {
  const int h = blockIdx.y;
  const int q0 = blockIdx.x * 32;
  const int t = threadIdx.x;
  const int qr = t >> 3;
  const int sub = t & 7;
  __shared__ float Ks[32][36];  // +4 pad: keeps float4 alignment
  __shared__ float Vs[32][36];
  __shared__ float Ps[32][36];
  __shared__ int KB[32];
  const float scale = 0.17677669529663687f;  // 1/sqrt(32)

  // Q row of this thread in registers (8 threads share a row -> L1 broadcast)
  float4 Qr[8];
  {
    const float4* qrow = (const float4*)(qkv + (size_t)(q0 + qr) * (3 * DIM) + h * HDIM);
    #pragma unroll
    for (int j = 0; j < 8; ++j) {
      float4 v = qrow[j];
      v.x *= scale; v.y *= scale; v.z *= scale; v.w *= scale;
      Qr[j] = v;
    }
  }
  int qb = 0;
  if (MASKED) qb = bidx[q0 + qr];

  float acc0 = 0.f, acc1 = 0.f, acc2 = 0.f, acc3 = 0.f;
  float m = -1e30f, l = 0.f;

  for (int k0 = 0; k0 < NATOMS; k0 += 32) {
    {  // stage K, V tiles
      const float* base = qkv + (size_t)(k0 + qr) * (3 * DIM) + h * HDIM + sub * 4;
      const float4 kv = *(const float4*)(base + DIM);
      const float4 vv = *(const float4*)(base + 2 * DIM);
      *(float4*)&Ks[qr][sub * 4] = kv;
      *(float4*)&Vs[qr][sub * 4] = vv;
      if (MASKED && t < 32) KB[t] = bidx[k0 + t];
    }
    __syncthreads();

    // scores for k = sub*4+j
    float s[4];
    #pragma unroll
    for (int j = 0; j < 4; ++j) {
      const int k = sub * 4 + j;
      float a = 0.f;
      #pragma unroll
      for (int c4 = 0; c4 < 8; ++c4) {
        const float4 k4 = *(const float4*)&Ks[k][c4 << 2];
        const float4 q4 = Qr[c4];
        a += q4.x * k4.x + q4.y * k4.y + q4.z * k4.z + q4.w * k4.w;
      }
      if (MASKED && KB[k] != qb) a = -1e30f;
      s[j] = a;
    }
    float mx = fmaxf(fmaxf(s[0], s[1]), fmaxf(s[2], s[3]));
    mx = fmaxf(mx, __shfl_xor(mx, 1, 8));
    mx = fmaxf(mx, __shfl_xor(mx, 2, 8));
    mx = fmaxf(mx, __shfl_xor(mx, 4, 8));
    const float newm = fmaxf(m, mx);
    const float f = __expf(m - newm);
    float p[4], rs = 0.f;
    #pragma unroll
    for (int j = 0; j < 4; ++j) {
      p[j] = (s[j] <= -0.5e30f) ? 0.f : __expf(s[j] - newm);
      rs += p[j];
    }
    rs += __shfl_xor(rs, 1, 8);
    rs += __shfl_xor(rs, 2, 8);
    rs += __shfl_xor(rs, 4, 8);
    l = l * f + rs;
    m = newm;
    acc0 *= f; acc1 *= f; acc2 *= f; acc3 *= f;
    *(float4*)&Ps[qr][sub * 4] = make_float4(p[0], p[1], p[2], p[3]);
    __syncthreads();

    // PV: acc[d] += sum_k P[qr][k] * V[k][d], d = sub*4..+3
    #pragma unroll 4
    for (int k = 0; k < 32; ++k) {
      const float pv = Ps[qr][k];
      const float4 v4 = *(const float4*)&Vs[k][sub * 4];
      acc0 += pv * v4.x;
      acc1 += pv * v4.y;
      acc2 += pv * v4.z;
      acc3 += pv * v4.w;
    }
    __syncthreads();
  }
  const float inv = 1.f / l;
  float4 o = make_float4(acc0 * inv, acc1 * inv, acc2 * inv, acc3 * inv);
  *(float4*)&out[(size_t)(q0 + qr) * DIM + h * HDIM + sub * 4] = o;
}

// ---------------- out-proj + (residual) + LayerNorm ----------------
// 8 atoms per block; thread t owns dim t.
template <bool RESID>
__global__ __launch_bounds__(256) void outproj_ln_kernel(
    const float* __restrict__ att, const float* __restrict__ w,
    const float* __restrict__ b, const float* __restrict__ resid1,
    const float* __restrict__ resid2, const float* __restrict__ g,
    const float* __restrict__ bb, float* __restrict__ out) {
  __shared__ float X[8][256];
  __shared__ float red[2][8][4];
  __shared__ float stat[2][8];
  const int a0 = blockIdx.x * 8, t = threadIdx.x;
  for (int idx = t; idx < 8 * 256; idx += 256) {
    const int a = idx >> 8, c = idx & 255;
    X[a][c] = att[(size_t)(a0 + a) * DIM + c];
  }
  __syncthreads();
  float y[8];
  const float bo = b[t];
  #pragma unroll
  for (int a = 0; a < 8; ++a) y[a] = bo;
  const float4* wr = (const float4*)(w + (size_t)t * 256);
  for (int k4 = 0; k4 < 64; ++k4) {
    const float4 w4 = wr[k4];
    #pragma unroll
    for (int a = 0; a < 8; ++a) {
      const float4 x4 = *(const float4*)&X[a][k4 << 2];
      y[a] += w4.x * x4.x + w4.y * x4.y + w4.z * x4.z + w4.w * x4.w;
    }
  }
  if (RESID) {
    #pragma unroll
    for (int a = 0; a < 8; ++a) {
      const size_t i = (size_t)(a0 + a) * DIM + t;
      y[a] += resid1[i] + resid2[i];
    }
  }
  const int lane = t & 63, wv = t >> 6;
  #pragma unroll
  for (int a = 0; a < 8; ++a) {
    float s = y[a], q = y[a] * y[a];
    #pragma unroll
    for (int o = 1; o < 64; o <<= 1) {
      s += __shfl_xor(s, o, 64);
      q += __shfl_xor(q, o, 64);
    }
    if (lane == 0) { red[0][a][wv] = s; red[1][a][wv] = q; }
  }
  __syncthreads();
  if (t < 8) {
    const float s = red[0][t][0] + red[0][t][1] + red[0][t][2] + red[0][t][3];
    const float q = red[1][t][0] + red[1][t][1] + red[1][t][2] + red[1][t][3];
    const float mean = s * (1.f / 256.f);
    const float var = q * (1.f / 256.f) - mean * mean;
    stat[0][t] = mean;
    stat[1][t] = rsqrtf(var + LNEPS);
  }
  __syncthreads();
  const float gg = g[t], bbv = bb[t];
  #pragma unroll
  for (int a = 0; a < 8; ++a) {
    out[(size_t)(a0 + a) * DIM + t] = (y[a] - stat[0][a]) * stat[1][a] * gg + bbv;
  }
}

// ---------------- pooling ----------------
__global__ __launch_bounds__(256) void pool_scatter_kernel(
    const float* __restrict__ pooled, const int* __restrict__ bidx,
    float* __restrict__ out, float* __restrict__ cnt) {
  const int a = blockIdx.x, t = threadIdx.x;
  const int b = bidx[a];
  atomicAdd(&out[(size_t)b * DIM + t], pooled[(size_t)a * DIM + t]);
  if (t == 0) atomicAdd(&cnt[b], 1.f);
}

__global__ __launch_bounds__(256) void pool_div_kernel(
    const float* __restrict__ cnt, float* __restrict__ out) {
  const int b = blockIdx.x, t = threadIdx.x;
  out[(size_t)b * DIM + t] /= fmaxf(cnt[b], 1.f);
}

extern "C" void kernel_launch(void* const* d_in, const int* in_sizes, int n_in,
                              void* d_out, int out_size, void* d_ws, size_t ws_size,
                              hipStream_t stream) {
  const float* atom_features = (const float*)d_in[0];
  const float* bond_features = (const float*)d_in[1];
  const int* edge_indices = (const int*)d_in[2];
  const int* batch_idx = (const int*)d_in[3];
  const float* atom_w = (const float*)d_in[4];
  const float* atom_b = (const float*)d_in[5];
  const float* bond_w = (const float*)d_in[6];
  const float* bond_b = (const float*)d_in[7];
  const float* conv_w = (const float*)d_in[8];
  const float* conv_b = (const float*)d_in[9];
  const float* attn_in_w = (const float*)d_in[10];
  const float* attn_in_b = (const float*)d_in[11];
  const float* attn_out_w = (const float*)d_in[12];
  const float* attn_out_b = (const float*)d_in[13];
  const float* ln_g = (const float*)d_in[14];
  const float* ln_b = (const float*)d_in[15];
  const float* gattn_in_w = (const float*)d_in[16];
  const float* gattn_in_b = (const float*)d_in[17];
  const float* gattn_out_w = (const float*)d_in[18];
  const float* gattn_out_b = (const float*)d_in[19];
  const float* gn_g = (const float*)d_in[20];
  const float* gn_b = (const float*)d_in[21];

  float* ws = (float*)d_ws;
  size_t off = 0;
  float* atom_h = ws + off; off += (size_t)NATOMS * DIM;
  float* bond_h = ws + off; off += (size_t)NBONDS * DIM;
  float* agg    = ws + off; off += (size_t)NATOMS * DIM;
  float* qkv    = ws + off; off += (size_t)NATOMS * 3 * DIM;
  float* att    = ws + off; off += (size_t)NATOMS * DIM;
  float* pooled = ws + off; off += (size_t)NATOMS * DIM;
  float* cnt    = ws + off; off += NGRAPH;
  if (ws_size < off * sizeof(float)) return;  // insufficient scratch

  const int* src = edge_indices;
  const int* tgt = edge_indices + NBONDS;

  atom_proj_kernel<<<NATOMS, 256, 0, stream>>>(atom_features, atom_w, atom_b, atom_h);
  bond_proj_kernel<<<NBONDS, 256, 0, stream>>>(bond_features, bond_w, bond_b, bond_h);

  for (int i = 0; i < NLAYER; ++i) {
    hipMemsetAsync(agg, 0, (size_t)NATOMS * DIM * sizeof(float), stream);
    conv_kernel<<<NBONDS / 8, 256, 0, stream>>>(
        atom_h, bond_h, src, tgt,
        conv_w + (size_t)i * DIM * 2 * DIM, conv_b + (size_t)i * DIM, agg);
    qkv_kernel<<<NATOMS / 8, 256, 0, stream>>>(
        atom_h, attn_in_w + (size_t)i * 3 * DIM * DIM, attn_in_b + (size_t)i * 3 * DIM, qkv);
    attn_kernel<false><<<dim3(NATOMS / 32, NH), 256, 0, stream>>>(qkv, nullptr, att);
    outproj_ln_kernel<true><<<NATOMS / 8, 256, 0, stream>>>(
        att, attn_out_w + (size_t)i * DIM * DIM, attn_out_b + (size_t)i * DIM,
        atom_h, agg, ln_g + (size_t)i * DIM, ln_b + (size_t)i * DIM, atom_h);
  }

  // global pooled attention (masked to same-graph pairs), LN without residual
  qkv_kernel<<<NATOMS / 8, 256, 0, stream>>>(atom_h, gattn_in_w, gattn_in_b, qkv);
  attn_kernel<true><<<dim3(NATOMS / 32, NH), 256, 0, stream>>>(qkv, batch_idx, att);
  outproj_ln_kernel<false><<<NATOMS / 8, 256, 0, stream>>>(
      att, gattn_out_w, gattn_out_b, nullptr, nullptr, gn_g, gn_b, pooled);

  // segment mean
  hipMemsetAsync(d_out, 0, (size_t)NGRAPH * DIM * sizeof(float), stream);
  hipMemsetAsync(cnt, 0, NGRAPH * sizeof(float), stream);
  pool_scatter_kernel<<<NATOMS, 256, 0, stream>>>(pooled, batch_idx, (float*)d_out, cnt);
  pool_div_kernel<<<NGRAPH, 256, 0, stream>>>(cnt, (float*)d_out);
}

// Round 2
// 1524.268 us; speedup vs baseline: 1.6655x; 1.6655x over previous
//
#include <hip/hip_runtime.h>
#include <hip/hip_bf16.h>
#include <math.h>

#define NATOMS 3072
#define NBONDS 12288
#define NGRAPH 64
#define DIM 256
#define NH 8
#define HDIM 32
#define NLAYER 4
#define AFD 74
#define BFD 12
#define LNEPS 1e-5f

typedef __attribute__((ext_vector_type(8))) short bf16x8;
typedef __attribute__((ext_vector_type(4))) short s16x4;
typedef __attribute__((ext_vector_type(4))) float f32x4;

static __device__ __forceinline__ short f2bf(float x) {
  union { float f; unsigned u; } v; v.f = x;
  unsigned r = v.u + 0x7fff + ((v.u >> 16) & 1);  // RNE
  return (short)(r >> 16);
}

// ---------------- input projections ----------------
__global__ __launch_bounds__(256) void atom_proj_kernel(
    const float* __restrict__ feat, const float* __restrict__ w,
    const float* __restrict__ b, float* __restrict__ out) {
  __shared__ float x[AFD];
  const int a = blockIdx.x, t = threadIdx.x;
  if (t < AFD) x[t] = feat[a * AFD + t];
  __syncthreads();
  float acc = b[t];
  const float* wr = w + t * AFD;
  for (int k = 0; k < AFD; ++k) acc = fmaf(wr[k], x[k], acc);
  out[a * DIM + t] = acc;
}

__global__ __launch_bounds__(256) void bond_proj_kernel(
    const float* __restrict__ feat, const float* __restrict__ w,
    const float* __restrict__ b, float* __restrict__ out) {
  __shared__ float x[BFD];
  const int e = blockIdx.x, t = threadIdx.x;
  if (t < BFD) x[t] = feat[e * BFD + t];
  __syncthreads();
  float acc = b[t];
  const float* wr = w + t * BFD;
  #pragma unroll
  for (int k = 0; k < BFD; ++k) acc = fmaf(wr[k], x[k], acc);
  out[e * DIM + t] = acc;
}

// ---------------- bond conv ----------------
__global__ __launch_bounds__(256) void conv_kernel(
    const float* __restrict__ atom_h, const float* __restrict__ bond_h,
    const int* __restrict__ src, const int* __restrict__ tgt,
    const float* __restrict__ w, const float* __restrict__ b,
    float* __restrict__ agg) {
  __shared__ float M[8][512];  // 16 KB
  const int e0 = blockIdx.x * 8, t = threadIdx.x;
  for (int idx = t; idx < 8 * 512; idx += 256) {
    const int be = idx >> 9, c = idx & 511;
    const int e = e0 + be;
    float v;
    if (c < 256) v = atom_h[src[e] * DIM + c] + bond_h[e * DIM + c];
    else         v = atom_h[tgt[e] * DIM + (c - 256)];
    M[be][c] = v;
  }
  __syncthreads();
  float acc[8];
  const float bb = b[t];
  #pragma unroll
  for (int i = 0; i < 8; ++i) acc[i] = bb;
  const float4* wr = (const float4*)(w + (size_t)t * 512);
  for (int k4 = 0; k4 < 128; ++k4) {
    const float4 w4 = wr[k4];
    #pragma unroll
    for (int be = 0; be < 8; ++be) {
      const float4 m4 = *(const float4*)&M[be][k4 << 2];
      acc[be] += w4.x * m4.x + w4.y * m4.y + w4.z * m4.z + w4.w * m4.w;
    }
  }
  #pragma unroll
  for (int be = 0; be < 8; ++be) {
    const float v = fmaxf(acc[be], 0.f);
    atomicAdd(&agg[(size_t)tgt[e0 + be] * DIM + t], v);
  }
}

// ---------------- qkv projection ----------------
__global__ __launch_bounds__(256) void qkv_kernel(
    const float* __restrict__ x, const float* __restrict__ w,
    const float* __restrict__ b, float* __restrict__ qkv) {
  __shared__ float X[8][256];
  const int a0 = blockIdx.x * 8, t = threadIdx.x;
  for (int idx = t; idx < 8 * 256; idx += 256) {
    const int a = idx >> 8, c = idx & 255;
    X[a][c] = x[(size_t)(a0 + a) * DIM + c];
  }
  __syncthreads();
  float aq[8], ak[8], av[8];
  const float bq = b[t], bk = b[t + 256], bv = b[t + 512];
  #pragma unroll
  for (int a = 0; a < 8; ++a) { aq[a] = bq; ak[a] = bk; av[a] = bv; }
  const float4* wq = (const float4*)(w + (size_t)t * 256);
  const float4* wk = (const float4*)(w + (size_t)(t + 256) * 256);
  const float4* wv = (const float4*)(w + (size_t)(t + 512) * 256);
  for (int k4 = 0; k4 < 64; ++k4) {
    const float4 q4 = wq[k4], k4v = wk[k4], v4 = wv[k4];
    #pragma unroll
    for (int a = 0; a < 8; ++a) {
      const float4 x4 = *(const float4*)&X[a][k4 << 2];
      aq[a] += q4.x * x4.x + q4.y * x4.y + q4.z * x4.z + q4.w * x4.w;
      ak[a] += k4v.x * x4.x + k4v.y * x4.y + k4v.z * x4.z + k4v.w * x4.w;
      av[a] += v4.x * x4.x + v4.y * x4.y + v4.z * x4.z + v4.w * x4.w;
    }
  }
  #pragma unroll
  for (int a = 0; a < 8; ++a) {
    const size_t row = (size_t)(a0 + a) * (3 * DIM);
    qkv[row + t] = aq[a];
    qkv[row + 256 + t] = ak[a];
    qkv[row + 512 + t] = av[a];
  }
}

// ---------------- MFMA flash attention ----------------
// Block: 1 head x 32 q-rows, 128 threads (2 waves x 16 q-rows each).
// S^T = mfma(K_frag, Q_frag): lane holds q = l&15, keys = (l>>4)*4+reg -> softmax
// state is lane-local in q. O^T = mfma(VT_frag, P_frag): accumulator also q = l&15.
template <bool MASKED>
__global__ __launch_bounds__(128) void attn_mfma_kernel(
    const float* __restrict__ qkv, const int* __restrict__ bidx,
    float* __restrict__ out) {
  __shared__ short Ks[64 * 32];      // [key][d]       row 64B
  __shared__ short VTs[32 * 72];     // [d][key pad72] row 144B (=9*16B, aligned+bank-spread)
  __shared__ short Ps[2 * 16 * 72];  // per-wave [q][key pad72]
  __shared__ int KB[64];

  const int h = blockIdx.y;
  const int t = threadIdx.x;
  const int wid = t >> 6;
  const int l = t & 63;
  const int lq = l & 15;   // q (col) index of this lane
  const int g = l >> 4;    // 16-lane group = K-chunk / row-group
  const int qrow = blockIdx.x * 32 + wid * 16 + lq;

  const float qscale = 0.17677669529663687f * 1.4426950408889634f;  // 1/sqrt(32) * log2(e)

  bf16x8 Qf;
  {
    const float* qp = qkv + (size_t)qrow * 768 + h * HDIM + g * 8;
    #pragma unroll
    for (int j = 0; j < 8; ++j) Qf[j] = f2bf(qp[j] * qscale);
  }
  int qb = 0;
  if (MASKED) qb = bidx[qrow];

  f32x4 accO[2] = {{0.f, 0.f, 0.f, 0.f}, {0.f, 0.f, 0.f, 0.f}};
  float m = -1e30f, lsum = 0.f;

  for (int k0 = 0; k0 < NATOMS; k0 += 64) {
    __syncthreads();  // previous iter's reads of Ks/VTs done
    #pragma unroll
    for (int it = 0; it < 8; ++it) {
      const int idx = it * 128 + t;  // 1024 d-pairs over 64 keys
      const int key = idx >> 4;
      const int dp = idx & 15;
      const float* kp = qkv + (size_t)(k0 + key) * 768 + 256 + h * HDIM + dp * 2;
      const float2 kv = *(const float2*)kp;
      const float2 vv = *(const float2*)(kp + 256);
      const unsigned pk =
          (unsigned short)f2bf(kv.x) | ((unsigned)(unsigned short)f2bf(kv.y) << 16);
      *(unsigned*)&Ks[key * 32 + dp * 2] = pk;
      VTs[(dp * 2) * 72 + key] = f2bf(vv.x);
      VTs[(dp * 2 + 1) * 72 + key] = f2bf(vv.y);
    }
    if (MASKED && t < 64) KB[t] = bidx[k0 + t];
    __syncthreads();

    // scores: S^T[key][q], 4 subtiles of 16 keys
    f32x4 s[4];
    #pragma unroll
    for (int kk = 0; kk < 4; ++kk) {
      const bf16x8 Kf = *(const bf16x8*)&Ks[(kk * 16 + lq) * 32 + g * 8];
      s[kk] = __builtin_amdgcn_mfma_f32_16x16x32_bf16(Kf, Qf, (f32x4){0.f, 0.f, 0.f, 0.f}, 0, 0, 0);
    }
    if (MASKED) {
      #pragma unroll
      for (int kk = 0; kk < 4; ++kk)
        #pragma unroll
        for (int r = 0; r < 4; ++r)
          if (KB[kk * 16 + g * 4 + r] != qb) s[kk][r] = -1e30f;
    }
    // online softmax over this lane's q-row (keys split across the 4 lanes sharing q)
    float mx = -1e30f;
    #pragma unroll
    for (int kk = 0; kk < 4; ++kk) {
      mx = fmaxf(mx, fmaxf(fmaxf(s[kk][0], s[kk][1]), fmaxf(s[kk][2], s[kk][3])));
    }
    mx = fmaxf(mx, __shfl_xor(mx, 16));
    mx = fmaxf(mx, __shfl_xor(mx, 32));
    const float newm = fmaxf(m, mx);
    const float f = exp2f(m - newm);
    float ps = 0.f;
    #pragma unroll
    for (int kk = 0; kk < 4; ++kk) {
      s16x4 p4;
      #pragma unroll
      for (int r = 0; r < 4; ++r) {
        const float p = (MASKED && s[kk][r] <= -0.5e30f) ? 0.f : exp2f(s[kk][r] - newm);
        ps += p;
        p4[r] = f2bf(p);
      }
      *(s16x4*)&Ps[wid * 1152 + lq * 72 + kk * 16 + g * 4] = p4;
    }
    ps += __shfl_xor(ps, 16);
    ps += __shfl_xor(ps, 32);
    lsum = lsum * f + ps;
    m = newm;
    accO[0] *= f;
    accO[1] *= f;

    // O^T += V^T . P^T   (two 16-d halves x two 32-key steps)
    #pragma unroll
    for (int hh = 0; hh < 2; ++hh) {
      #pragma unroll
      for (int kt = 0; kt < 2; ++kt) {
        const bf16x8 Vf = *(const bf16x8*)&VTs[(hh * 16 + lq) * 72 + kt * 32 + g * 8];
        const bf16x8 Pf = *(const bf16x8*)&Ps[wid * 1152 + lq * 72 + kt * 32 + g * 8];
        accO[hh] = __builtin_amdgcn_mfma_f32_16x16x32_bf16(Vf, Pf, accO[hh], 0, 0, 0);
      }
    }
  }
  const float inv = 1.f / lsum;
  #pragma unroll
  for (int hh = 0; hh < 2; ++hh) {
    #pragma unroll
    for (int r = 0; r < 4; ++r) {
      const int d = hh * 16 + g * 4 + r;
      out[(size_t)qrow * DIM + h * HDIM + d] = accO[hh][r] * inv;
    }
  }
}

// ---------------- out-proj + (residual) + LayerNorm ----------------
template <bool RESID>
__global__ __launch_bounds__(256) void outproj_ln_kernel(
    const float* __restrict__ att, const float* __restrict__ w,
    const float* __restrict__ b, const float* __restrict__ resid1,
    const float* __restrict__ resid2, const float* __restrict__ g,
    const float* __restrict__ bb, float* __restrict__ out) {
  __shared__ float X[8][256];
  __shared__ float red[2][8][4];
  __shared__ float stat[2][8];
  const int a0 = blockIdx.x * 8, t = threadIdx.x;
  for (int idx = t; idx < 8 * 256; idx += 256) {
    const int a = idx >> 8, c = idx & 255;
    X[a][c] = att[(size_t)(a0 + a) * DIM + c];
  }
  __syncthreads();
  float y[8];
  const float bo = b[t];
  #pragma unroll
  for (int a = 0; a < 8; ++a) y[a] = bo;
  const float4* wr = (const float4*)(w + (size_t)t * 256);
  for (int k4 = 0; k4 < 64; ++k4) {
    const float4 w4 = wr[k4];
    #pragma unroll
    for (int a = 0; a < 8; ++a) {
      const float4 x4 = *(const float4*)&X[a][k4 << 2];
      y[a] += w4.x * x4.x + w4.y * x4.y + w4.z * x4.z + w4.w * x4.w;
    }
  }
  if (RESID) {
    #pragma unroll
    for (int a = 0; a < 8; ++a) {
      const size_t i = (size_t)(a0 + a) * DIM + t;
      y[a] += resid1[i] + resid2[i];
    }
  }
  const int lane = t & 63, wv = t >> 6;
  #pragma unroll
  for (int a = 0; a < 8; ++a) {
    float s = y[a], q = y[a] * y[a];
    #pragma unroll
    for (int o = 1; o < 64; o <<= 1) {
      s += __shfl_xor(s, o, 64);
      q += __shfl_xor(q, o, 64);
    }
    if (lane == 0) { red[0][a][wv] = s; red[1][a][wv] = q; }
  }
  __syncthreads();
  if (t < 8) {
    const float s = red[0][t][0] + red[0][t][1] + red[0][t][2] + red[0][t][3];
    const float q = red[1][t][0] + red[1][t][1] + red[1][t][2] + red[1][t][3];
    const float mean = s * (1.f / 256.f);
    const float var = q * (1.f / 256.f) - mean * mean;
    stat[0][t] = mean;
    stat[1][t] = rsqrtf(var + LNEPS);
  }
  __syncthreads();
  const float gg = g[t], bbv = bb[t];
  #pragma unroll
  for (int a = 0; a < 8; ++a) {
    out[(size_t)(a0 + a) * DIM + t] = (y[a] - stat[0][a]) * stat[1][a] * gg + bbv;
  }
}

// ---------------- pooling ----------------
__global__ __launch_bounds__(256) void pool_scatter_kernel(
    const float* __restrict__ pooled, const int* __restrict__ bidx,
    float* __restrict__ out, float* __restrict__ cnt) {
  const int a = blockIdx.x, t = threadIdx.x;
  const int b = bidx[a];
  atomicAdd(&out[(size_t)b * DIM + t], pooled[(size_t)a * DIM + t]);
  if (t == 0) atomicAdd(&cnt[b], 1.f);
}

__global__ __launch_bounds__(256) void pool_div_kernel(
    const float* __restrict__ cnt, float* __restrict__ out) {
  const int b = blockIdx.x, t = threadIdx.x;
  out[(size_t)b * DIM + t] /= fmaxf(cnt[b], 1.f);
}

extern "C" void kernel_launch(void* const* d_in, const int* in_sizes, int n_in,
                              void* d_out, int out_size, void* d_ws, size_t ws_size,
                              hipStream_t stream) {
  const float* atom_features = (const float*)d_in[0];
  const float* bond_features = (const float*)d_in[1];
  const int* edge_indices = (const int*)d_in[2];
  const int* batch_idx = (const int*)d_in[3];
  const float* atom_w = (const float*)d_in[4];
  const float* atom_b = (const float*)d_in[5];
  const float* bond_w = (const float*)d_in[6];
  const float* bond_b = (const float*)d_in[7];
  const float* conv_w = (const float*)d_in[8];
  const float* conv_b = (const float*)d_in[9];
  const float* attn_in_w = (const float*)d_in[10];
  const float* attn_in_b = (const float*)d_in[11];
  const float* attn_out_w = (const float*)d_in[12];
  const float* attn_out_b = (const float*)d_in[13];
  const float* ln_g = (const float*)d_in[14];
  const float* ln_b = (const float*)d_in[15];
  const float* gattn_in_w = (const float*)d_in[16];
  const float* gattn_in_b = (const float*)d_in[17];
  const float* gattn_out_w = (const float*)d_in[18];
  const float* gattn_out_b = (const float*)d_in[19];
  const float* gn_g = (const float*)d_in[20];
  const float* gn_b = (const float*)d_in[21];

  float* ws = (float*)d_ws;
  size_t off = 0;
  float* atom_h = ws + off; off += (size_t)NATOMS * DIM;
  float* bond_h = ws + off; off += (size_t)NBONDS * DIM;
  float* agg    = ws + off; off += (size_t)NATOMS * DIM;
  float* qkv    = ws + off; off += (size_t)NATOMS * 3 * DIM;
  float* att    = ws + off; off += (size_t)NATOMS * DIM;
  float* pooled = ws + off; off += (size_t)NATOMS * DIM;
  float* cnt    = ws + off; off += NGRAPH;
  if (ws_size < off * sizeof(float)) return;

  const int* src = edge_indices;
  const int* tgt = edge_indices + NBONDS;

  atom_proj_kernel<<<NATOMS, 256, 0, stream>>>(atom_features, atom_w, atom_b, atom_h);
  bond_proj_kernel<<<NBONDS, 256, 0, stream>>>(bond_features, bond_w, bond_b, bond_h);

  for (int i = 0; i < NLAYER; ++i) {
    hipMemsetAsync(agg, 0, (size_t)NATOMS * DIM * sizeof(float), stream);
    conv_kernel<<<NBONDS / 8, 256, 0, stream>>>(
        atom_h, bond_h, src, tgt,
        conv_w + (size_t)i * DIM * 2 * DIM, conv_b + (size_t)i * DIM, agg);
    qkv_kernel<<<NATOMS / 8, 256, 0, stream>>>(
        atom_h, attn_in_w + (size_t)i * 3 * DIM * DIM, attn_in_b + (size_t)i * 3 * DIM, qkv);
    attn_mfma_kernel<false><<<dim3(NATOMS / 32, NH), 128, 0, stream>>>(qkv, nullptr, att);
    outproj_ln_kernel<true><<<NATOMS / 8, 256, 0, stream>>>(
        att, attn_out_w + (size_t)i * DIM * DIM, attn_out_b + (size_t)i * DIM,
        atom_h, agg, ln_g + (size_t)i * DIM, ln_b + (size_t)i * DIM, atom_h);
  }

  qkv_kernel<<<NATOMS / 8, 256, 0, stream>>>(atom_h, gattn_in_w, gattn_in_b, qkv);
  attn_mfma_kernel<true><<<dim3(NATOMS / 32, NH), 128, 0, stream>>>(qkv, batch_idx, att);
  outproj_ln_kernel<false><<<NATOMS / 8, 256, 0, stream>>>(
      att, gattn_out_w, gattn_out_b, nullptr, nullptr, gn_g, gn_b, pooled);

  hipMemsetAsync(d_out, 0, (size_t)NGRAPH * DIM * sizeof(float), stream);
  hipMemsetAsync(cnt, 0, NGRAPH * sizeof(float), stream);
  pool_scatter_kernel<<<NATOMS, 256, 0, stream>>>(pooled, batch_idx, (float*)d_out, cnt);
  pool_div_kernel<<<NGRAPH, 256, 0, stream>>>(cnt, (float*)d_out);
}

// Round 3
// 908.102 us; speedup vs baseline: 2.7955x; 1.6785x over previous
//
#include <hip/hip_runtime.h>
#include <hip/hip_bf16.h>
#include <math.h>

#define NATOMS 3072
#define NBONDS 12288
#define NGRAPH 64
#define DIM 256
#define NH 8
#define HDIM 32
#define NLAYER 4
#define AFD 74
#define BFD 12
#define LNEPS 1e-5f

typedef __attribute__((ext_vector_type(8))) short bf16x8;
typedef __attribute__((ext_vector_type(4))) short s16x4;
typedef __attribute__((ext_vector_type(4))) float f32x4;

static __device__ __forceinline__ short f2bf(float x) {
  union { float f; unsigned u; } v; v.f = x;
  unsigned r = v.u + 0x7fff + ((v.u >> 16) & 1);  // RNE
  return (short)(r >> 16);
}

// ---------------- f32 -> bf16 bulk convert ----------------
__global__ __launch_bounds__(256) void f2bf_kernel(
    const float* __restrict__ in, short* __restrict__ out, int n4) {
  for (int i = blockIdx.x * 256 + threadIdx.x; i < n4; i += gridDim.x * 256) {
    const float4 v = ((const float4*)in)[i];
    s16x4 o;
    o[0] = f2bf(v.x); o[1] = f2bf(v.y); o[2] = f2bf(v.z); o[3] = f2bf(v.w);
    ((s16x4*)out)[i] = o;
  }
}

// ---------------- input projections ----------------
__global__ __launch_bounds__(256) void atom_proj_kernel(
    const float* __restrict__ feat, const float* __restrict__ w,
    const float* __restrict__ b, float* __restrict__ out, short* __restrict__ outbf) {
  __shared__ float x[AFD];
  const int a = blockIdx.x, t = threadIdx.x;
  if (t < AFD) x[t] = feat[a * AFD + t];
  __syncthreads();
  float acc = b[t];
  const float* wr = w + t * AFD;
  for (int k = 0; k < AFD; ++k) acc = fmaf(wr[k], x[k], acc);
  out[a * DIM + t] = acc;
  outbf[a * DIM + t] = f2bf(acc);
}

__global__ __launch_bounds__(256) void bond_proj_kernel(
    const float* __restrict__ feat, const float* __restrict__ w,
    const float* __restrict__ b, short* __restrict__ outbf) {
  __shared__ float x[BFD];
  const int e = blockIdx.x, t = threadIdx.x;
  if (t < BFD) x[t] = feat[e * BFD + t];
  __syncthreads();
  float acc = b[t];
  const float* wr = w + t * BFD;
  #pragma unroll
  for (int k = 0; k < BFD; ++k) acc = fmaf(wr[k], x[k], acc);
  outbf[e * DIM + t] = f2bf(acc);
}

// ---------------- bf16 MFMA GEMM: C[M][N] = A[M][256] @ W[N][WS(first 256)]^T ----------------
// Block 256 thr = 4 waves, tile 32m x 128n. Wave: 16m x 64n. No LDS.
// mfma(A=W-row frag, B=A-row frag) -> C[n][m]: m=lane&15, n=(lane>>4)*4+reg.
template <int WS>
__global__ __launch_bounds__(256) void gemm_bt_kernel(
    const short* __restrict__ A, const short* __restrict__ W,
    const float* __restrict__ bias, float* __restrict__ Cf,
    short* __restrict__ Cbf, int ldc) {
  const int t = threadIdx.x;
  const int w = t >> 6, l = t & 63;
  const int lq = l & 15, g = l >> 4;
  const int mrow = blockIdx.x * 32 + (w & 1) * 16 + lq;
  const int nbase = blockIdx.y * 128 + (w >> 1) * 64;
  const short* arow = A + (size_t)mrow * 256 + g * 8;
  const short* wr0 = W + (size_t)(nbase + lq) * WS + g * 8;

  f32x4 acc[4] = {{0.f,0.f,0.f,0.f},{0.f,0.f,0.f,0.f},{0.f,0.f,0.f,0.f},{0.f,0.f,0.f,0.f}};
  #pragma unroll
  for (int kc = 0; kc < 8; ++kc) {
    const bf16x8 Xf = *(const bf16x8*)(arow + kc * 32);
    #pragma unroll
    for (int sub = 0; sub < 4; ++sub) {
      const bf16x8 Wf = *(const bf16x8*)(wr0 + (size_t)sub * 16 * WS + kc * 32);
      acc[sub] = __builtin_amdgcn_mfma_f32_16x16x32_bf16(Wf, Xf, acc[sub], 0, 0, 0);
    }
  }
  #pragma unroll
  for (int sub = 0; sub < 4; ++sub) {
    const int n = nbase + sub * 16 + g * 4;
    float4 v = make_float4(acc[sub][0], acc[sub][1], acc[sub][2], acc[sub][3]);
    if (bias) {
      const float4 b4 = *(const float4*)&bias[n];
      v.x += b4.x; v.y += b4.y; v.z += b4.z; v.w += b4.w;
    }
    if (Cf) *(float4*)&Cf[(size_t)mrow * ldc + n] = v;
    if (Cbf) {
      s16x4 o;
      o[0] = f2bf(v.x); o[1] = f2bf(v.y); o[2] = f2bf(v.z); o[3] = f2bf(v.w);
      *(s16x4*)&Cbf[(size_t)mrow * ldc + n] = o;
    }
  }
}

// ---------------- per-edge message: relu(G1[src]+B1[e]+G2[tgt]+b) -> atomic agg[tgt] ----------------
__global__ __launch_bounds__(256) void msg_kernel(
    const float* __restrict__ G1, const float* __restrict__ B1,
    const float* __restrict__ G2, const float* __restrict__ bias,
    const int* __restrict__ src, const int* __restrict__ tgt,
    float* __restrict__ agg) {
  const int e = blockIdx.x * 4 + (threadIdx.x >> 6);
  const int c = (threadIdx.x & 63) * 4;
  const int s = src[e], tg = tgt[e];
  const float4 g1 = *(const float4*)&G1[(size_t)s * DIM + c];
  const float4 b1 = *(const float4*)&B1[(size_t)e * DIM + c];
  const float4 g2 = *(const float4*)&G2[(size_t)tg * DIM + c];
  const float4 bb = *(const float4*)&bias[c];
  float* ap = &agg[(size_t)tg * DIM + c];
  atomicAdd(ap + 0, fmaxf(g1.x + b1.x + g2.x + bb.x, 0.f));
  atomicAdd(ap + 1, fmaxf(g1.y + b1.y + g2.y + bb.y, 0.f));
  atomicAdd(ap + 2, fmaxf(g1.z + b1.z + g2.z + bb.z, 0.f));
  atomicAdd(ap + 3, fmaxf(g1.w + b1.w + g2.w + bb.w, 0.f));
}

// ---------------- MFMA flash attention (bf16 qkv in, bf16 out) ----------------
template <bool MASKED>
__global__ __launch_bounds__(128) void attn_mfma_kernel(
    const short* __restrict__ qkv, const int* __restrict__ bidx,
    short* __restrict__ outbf) {
  __shared__ short Ks[64 * 32];
  __shared__ short VTs[32 * 72];
  __shared__ short Ps[2 * 16 * 72];
  __shared__ int KB[64];

  const int h = blockIdx.y;
  const int t = threadIdx.x;
  const int wid = t >> 6;
  const int l = t & 63;
  const int lq = l & 15;
  const int g = l >> 4;
  const int qrow = blockIdx.x * 32 + wid * 16 + lq;

  const float sscale = 0.17677669529663687f * 1.4426950408889634f;  // 1/sqrt(32)*log2(e)

  const bf16x8 Qf = *(const bf16x8*)(qkv + (size_t)qrow * 768 + h * HDIM + g * 8);
  int qb = 0;
  if (MASKED) qb = bidx[qrow];

  f32x4 accO[2] = {{0.f, 0.f, 0.f, 0.f}, {0.f, 0.f, 0.f, 0.f}};
  float m = -1e30f, lsum = 0.f;

  for (int k0 = 0; k0 < NATOMS; k0 += 64) {
    __syncthreads();
    #pragma unroll
    for (int it = 0; it < 2; ++it) {
      const int idx = it * 128 + t;  // 256 chunks: key = idx>>2, dc = idx&3
      const int key = idx >> 2, dc = idx & 3;
      const short* base = qkv + (size_t)(k0 + key) * 768 + 256 + h * HDIM + dc * 8;
      *(bf16x8*)&Ks[key * 32 + dc * 8] = *(const bf16x8*)base;
      const bf16x8 vv = *(const bf16x8*)(base + 256);
      #pragma unroll
      for (int j = 0; j < 8; ++j) VTs[(dc * 8 + j) * 72 + key] = vv[j];
    }
    if (MASKED && t < 64) KB[t] = bidx[k0 + t];
    __syncthreads();

    f32x4 s[4];
    #pragma unroll
    for (int kk = 0; kk < 4; ++kk) {
      const bf16x8 Kf = *(const bf16x8*)&Ks[(kk * 16 + lq) * 32 + g * 8];
      s[kk] = __builtin_amdgcn_mfma_f32_16x16x32_bf16(Kf, Qf, (f32x4){0.f, 0.f, 0.f, 0.f}, 0, 0, 0);
    }
    #pragma unroll
    for (int kk = 0; kk < 4; ++kk) {
      #pragma unroll
      for (int r = 0; r < 4; ++r) {
        s[kk][r] *= sscale;
        if (MASKED && KB[kk * 16 + g * 4 + r] != qb) s[kk][r] = -1e30f;
      }
    }
    float mx = -1e30f;
    #pragma unroll
    for (int kk = 0; kk < 4; ++kk)
      mx = fmaxf(mx, fmaxf(fmaxf(s[kk][0], s[kk][1]), fmaxf(s[kk][2], s[kk][3])));
    mx = fmaxf(mx, __shfl_xor(mx, 16));
    mx = fmaxf(mx, __shfl_xor(mx, 32));
    const float newm = fmaxf(m, mx);
    const float f = exp2f(m - newm);
    float ps = 0.f;
    #pragma unroll
    for (int kk = 0; kk < 4; ++kk) {
      s16x4 p4;
      #pragma unroll
      for (int r = 0; r < 4; ++r) {
        const float p = (MASKED && s[kk][r] <= -0.5e30f) ? 0.f : exp2f(s[kk][r] - newm);
        ps += p;
        p4[r] = f2bf(p);
      }
      *(s16x4*)&Ps[wid * 1152 + lq * 72 + kk * 16 + g * 4] = p4;
    }
    ps += __shfl_xor(ps, 16);
    ps += __shfl_xor(ps, 32);
    lsum = lsum * f + ps;
    m = newm;
    accO[0] *= f;
    accO[1] *= f;

    #pragma unroll
    for (int hh = 0; hh < 2; ++hh) {
      #pragma unroll
      for (int kt = 0; kt < 2; ++kt) {
        const bf16x8 Vf = *(const bf16x8*)&VTs[(hh * 16 + lq) * 72 + kt * 32 + g * 8];
        const bf16x8 Pf = *(const bf16x8*)&Ps[wid * 1152 + lq * 72 + kt * 32 + g * 8];
        accO[hh] = __builtin_amdgcn_mfma_f32_16x16x32_bf16(Vf, Pf, accO[hh], 0, 0, 0);
      }
    }
  }
  const float inv = 1.f / lsum;
  #pragma unroll
  for (int hh = 0; hh < 2; ++hh) {
    s16x4 o;
    #pragma unroll
    for (int r = 0; r < 4; ++r) o[r] = f2bf(accO[hh][r] * inv);
    *(s16x4*)&outbf[(size_t)qrow * DIM + h * HDIM + hh * 16 + g * 4] = o;
  }
}

// ---------------- residual + LayerNorm (1 wave per row) ----------------
template <bool RESID>
__global__ __launch_bounds__(64) void ln_kernel(
    const float* __restrict__ P, const float* __restrict__ r1,
    const float* __restrict__ r2, const float* __restrict__ g,
    const float* __restrict__ b, float* __restrict__ outf,
    short* __restrict__ outbf) {
  const int row = blockIdx.x, t = threadIdx.x;
  const size_t base = (size_t)row * DIM + t * 4;
  float4 y = *(const float4*)&P[base];
  if (RESID) {
    const float4 a = *(const float4*)&r1[base];
    const float4 c = *(const float4*)&r2[base];
    y.x += a.x + c.x; y.y += a.y + c.y; y.z += a.z + c.z; y.w += a.w + c.w;
  }
  float s = y.x + y.y + y.z + y.w;
  float q = y.x * y.x + y.y * y.y + y.z * y.z + y.w * y.w;
  #pragma unroll
  for (int o = 1; o < 64; o <<= 1) {
    s += __shfl_xor(s, o, 64);
    q += __shfl_xor(q, o, 64);
  }
  const float mean = s * (1.f / 256.f);
  const float var = q * (1.f / 256.f) - mean * mean;
  const float rstd = rsqrtf(var + LNEPS);
  const float4 g4 = *(const float4*)&g[t * 4];
  const float4 b4 = *(const float4*)&b[t * 4];
  float4 o;
  o.x = (y.x - mean) * rstd * g4.x + b4.x;
  o.y = (y.y - mean) * rstd * g4.y + b4.y;
  o.z = (y.z - mean) * rstd * g4.z + b4.z;
  o.w = (y.w - mean) * rstd * g4.w + b4.w;
  if (outf) *(float4*)&outf[base] = o;
  if (outbf) {
    s16x4 ob;
    ob[0] = f2bf(o.x); ob[1] = f2bf(o.y); ob[2] = f2bf(o.z); ob[3] = f2bf(o.w);
    *(s16x4*)&outbf[base] = ob;
  }
}

// ---------------- pooling ----------------
__global__ __launch_bounds__(256) void pool_scatter_kernel(
    const float* __restrict__ pooled, const int* __restrict__ bidx,
    float* __restrict__ out, float* __restrict__ cnt) {
  const int a = blockIdx.x, t = threadIdx.x;
  const int b = bidx[a];
  atomicAdd(&out[(size_t)b * DIM + t], pooled[(size_t)a * DIM + t]);
  if (t == 0) atomicAdd(&cnt[b], 1.f);
}

__global__ __launch_bounds__(256) void pool_div_kernel(
    const float* __restrict__ cnt, float* __restrict__ out) {
  const int b = blockIdx.x, t = threadIdx.x;
  out[(size_t)b * DIM + t] /= fmaxf(cnt[b], 1.f);
}

extern "C" void kernel_launch(void* const* d_in, const int* in_sizes, int n_in,
                              void* d_out, int out_size, void* d_ws, size_t ws_size,
                              hipStream_t stream) {
  const float* atom_features = (const float*)d_in[0];
  const float* bond_features = (const float*)d_in[1];
  const int* edge_indices = (const int*)d_in[2];
  const int* batch_idx = (const int*)d_in[3];
  const float* atom_w = (const float*)d_in[4];
  const float* atom_b = (const float*)d_in[5];
  const float* bond_w = (const float*)d_in[6];
  const float* bond_b = (const float*)d_in[7];
  const float* conv_w = (const float*)d_in[8];
  const float* conv_b = (const float*)d_in[9];
  const float* attn_in_w = (const float*)d_in[10];
  const float* attn_in_b = (const float*)d_in[11];
  const float* attn_out_w = (const float*)d_in[12];
  const float* attn_out_b = (const float*)d_in[13];
  const float* ln_g = (const float*)d_in[14];
  const float* ln_b = (const float*)d_in[15];
  const float* gattn_in_w = (const float*)d_in[16];
  const float* gattn_in_b = (const float*)d_in[17];
  const float* gattn_out_w = (const float*)d_in[18];
  const float* gattn_out_b = (const float*)d_in[19];
  const float* gn_g = (const float*)d_in[20];
  const float* gn_b = (const float*)d_in[21];

  // ---- workspace carve-up ----
  char* wsb = (char*)d_ws;
  size_t off = 0;
  auto alloc_f = [&](size_t n) { float* p = (float*)(wsb + off); off += n * 4; return p; };
  auto alloc_s = [&](size_t n) { short* p = (short*)(wsb + off); off += n * 2; return p; };

  float* atom_h = alloc_f((size_t)NATOMS * DIM);
  float* B1     = alloc_f((size_t)NBONDS * DIM);
  float* G1     = alloc_f((size_t)NATOMS * DIM);  // also reused as P (post-attn pre-LN)
  float* G2     = alloc_f((size_t)NATOMS * DIM);
  float* agg    = alloc_f((size_t)NATOMS * DIM);
  float* pooled = alloc_f((size_t)NATOMS * DIM);
  float* cnt    = alloc_f(NGRAPH);
  short* atom_hb = alloc_s((size_t)NATOMS * DIM);
  short* bond_hb = alloc_s((size_t)NBONDS * DIM);
  short* qkv_b   = alloc_s((size_t)NATOMS * 3 * DIM);
  short* att_b   = alloc_s((size_t)NATOMS * DIM);
  short* conv_wb = alloc_s((size_t)NLAYER * DIM * 2 * DIM);
  short* in_wb   = alloc_s((size_t)NLAYER * 3 * DIM * DIM);
  short* out_wb  = alloc_s((size_t)NLAYER * DIM * DIM);
  short* gin_wb  = alloc_s((size_t)3 * DIM * DIM);
  short* gout_wb = alloc_s((size_t)DIM * DIM);
  if (ws_size < off) return;
  float* P = G1;  // disjoint lifetime: G1 consumed by msg_kernel before out-proj runs

  const int* src = edge_indices;
  const int* tgt = edge_indices + NBONDS;

  // ---- weight conversion ----
  auto conv1 = [&](const float* s, short* d, int n) {
    f2bf_kernel<<<(n / 4 + 255) / 256, 256, 0, stream>>>(s, d, n / 4);
  };
  conv1(conv_w, conv_wb, NLAYER * DIM * 2 * DIM);
  conv1(attn_in_w, in_wb, NLAYER * 3 * DIM * DIM);
  conv1(attn_out_w, out_wb, NLAYER * DIM * DIM);
  conv1(gattn_in_w, gin_wb, 3 * DIM * DIM);
  conv1(gattn_out_w, gout_wb, DIM * DIM);

  atom_proj_kernel<<<NATOMS, 256, 0, stream>>>(atom_features, atom_w, atom_b, atom_h, atom_hb);
  bond_proj_kernel<<<NBONDS, 256, 0, stream>>>(bond_features, bond_w, bond_b, bond_hb);

  for (int i = 0; i < NLAYER; ++i) {
    const short* cw = conv_wb + (size_t)i * DIM * 2 * DIM;
    hipMemsetAsync(agg, 0, (size_t)NATOMS * DIM * sizeof(float), stream);
    gemm_bt_kernel<512><<<dim3(NBONDS / 32, 2), 256, 0, stream>>>(
        bond_hb, cw, nullptr, B1, nullptr, DIM);
    gemm_bt_kernel<512><<<dim3(NATOMS / 32, 2), 256, 0, stream>>>(
        atom_hb, cw, nullptr, G1, nullptr, DIM);
    gemm_bt_kernel<512><<<dim3(NATOMS / 32, 2), 256, 0, stream>>>(
        atom_hb, cw + 256, nullptr, G2, nullptr, DIM);
    msg_kernel<<<NBONDS / 4, 256, 0, stream>>>(
        G1, B1, G2, conv_b + (size_t)i * DIM, src, tgt, agg);
    gemm_bt_kernel<256><<<dim3(NATOMS / 32, 6), 256, 0, stream>>>(
        atom_hb, in_wb + (size_t)i * 3 * DIM * DIM, attn_in_b + (size_t)i * 3 * DIM,
        nullptr, qkv_b, 3 * DIM);
    attn_mfma_kernel<false><<<dim3(NATOMS / 32, NH), 128, 0, stream>>>(qkv_b, nullptr, att_b);
    gemm_bt_kernel<256><<<dim3(NATOMS / 32, 2), 256, 0, stream>>>(
        att_b, out_wb + (size_t)i * DIM * DIM, attn_out_b + (size_t)i * DIM,
        P, nullptr, DIM);
    ln_kernel<true><<<NATOMS, 64, 0, stream>>>(
        P, atom_h, agg, ln_g + (size_t)i * DIM, ln_b + (size_t)i * DIM, atom_h, atom_hb);
  }

  // ---- pooled masked attention ----
  gemm_bt_kernel<256><<<dim3(NATOMS / 32, 6), 256, 0, stream>>>(
      atom_hb, gin_wb, gattn_in_b, nullptr, qkv_b, 3 * DIM);
  attn_mfma_kernel<true><<<dim3(NATOMS / 32, NH), 128, 0, stream>>>(qkv_b, batch_idx, att_b);
  gemm_bt_kernel<256><<<dim3(NATOMS / 32, 2), 256, 0, stream>>>(
      att_b, gout_wb, gattn_out_b, P, nullptr, DIM);
  ln_kernel<false><<<NATOMS, 64, 0, stream>>>(
      P, nullptr, nullptr, gn_g, gn_b, pooled, nullptr);

  // ---- segment mean ----
  hipMemsetAsync(d_out, 0, (size_t)NGRAPH * DIM * sizeof(float), stream);
  hipMemsetAsync(cnt, 0, NGRAPH * sizeof(float), stream);
  pool_scatter_kernel<<<NATOMS, 256, 0, stream>>>(pooled, batch_idx, (float*)d_out, cnt);
  pool_div_kernel<<<NGRAPH, 256, 0, stream>>>(cnt, (float*)d_out);
}